// Round 8
// baseline (480.626 us; speedup 1.0000x reference)
//
#include <hip/hip_runtime.h>

#define N 100000
#define E 1000000
#define ETOT 1100000   // E + N self-loops
#define NB1 391        // ceil(N/256)

typedef __attribute__((ext_vector_type(8))) short bf16x8;
typedef __attribute__((ext_vector_type(4))) float f32x4;

__device__ __forceinline__ float lrelu(float x) { return x > 0.f ? x : 0.2f * x; }
// f32 -> bf16 bits, round-to-nearest-even
__device__ __forceinline__ unsigned short f2b(float x) {
    unsigned u = __float_as_uint(x);
    return (unsigned short)((u + 0x7FFFu + ((u >> 16) & 1u)) >> 16);
}
__device__ __forceinline__ float b2f(unsigned short v) {
    return __uint_as_float(((unsigned)v) << 16);
}

// ---------------- CSR build ----------------
__global__ __launch_bounds__(256) void hist_kernel(const int* __restrict__ ei,
                                                   int* __restrict__ hist) {
    const int e = blockIdx.x * 256 + threadIdx.x;
    if (e >= ETOT) return;
    int d = (e < E) ? ei[E + e] : (e - E);
    atomicAdd(&hist[d], 1);
}

__global__ __launch_bounds__(256) void scan1_kernel(const int* __restrict__ hist,
                                                    int* __restrict__ rofs,
                                                    int* __restrict__ bsum) {
    __shared__ int sm[256];
    const int t = threadIdx.x;
    const int i = blockIdx.x * 256 + t;
    int v = (i < N) ? hist[i] : 0;
    sm[t] = v;
    __syncthreads();
#pragma unroll
    for (int off = 1; off < 256; off <<= 1) {
        int x = (t >= off) ? sm[t - off] : 0;
        __syncthreads();
        sm[t] += x;
        __syncthreads();
    }
    if (i < N) rofs[i] = sm[t] - v;
    if (t == 255) bsum[blockIdx.x] = sm[255];
}

__global__ __launch_bounds__(512) void scan2_kernel(int* __restrict__ bsum) {
    __shared__ int sm[512];
    const int t = threadIdx.x;
    int v = (t < NB1) ? bsum[t] : 0;
    sm[t] = v;
    __syncthreads();
#pragma unroll
    for (int off = 1; off < 512; off <<= 1) {
        int x = (t >= off) ? sm[t - off] : 0;
        __syncthreads();
        sm[t] += x;
        __syncthreads();
    }
    if (t < NB1) bsum[t] = sm[t] - v;
}

__global__ __launch_bounds__(256) void scan3_kernel(int* __restrict__ rofs,
                                                    const int* __restrict__ bsum,
                                                    int* __restrict__ cursor) {
    const int i = blockIdx.x * 256 + threadIdx.x;
    if (i < N) {
        int r = rofs[i] + bsum[blockIdx.x];
        rofs[i] = r;
        cursor[i] = r;
    }
    if (i == 0) rofs[N] = ETOT;
}

__global__ __launch_bounds__(256) void scatter_kernel(const int* __restrict__ ei,
                                                      int* __restrict__ cursor,
                                                      int* __restrict__ esrc) {
    const int e = blockIdx.x * 256 + threadIdx.x;
    if (e >= ETOT) return;
    int s, d;
    if (e < E) { s = ei[e]; d = ei[E + e]; } else { s = d = e - E; }
    int pos = atomicAdd(&cursor[d], 1);
    esrc[pos] = s;
}

// ---------------- weight prep (bf16) ----------------
// W1T [272][128]: rows 0..255 = W1^T; rows 256..271 = layer-1 logit fold (src heads 0-7, dst heads 0-7)
// W2TE [48][256]: rows 0..31 = W2^T; row 32 = layer-2 src fold; row 33 = dst fold; rows 34..47 = 0
__global__ __launch_bounds__(256) void wt_kernel(const float* __restrict__ W1,
                                                 const float* __restrict__ W2,
                                                 const float* __restrict__ att_src1,
                                                 const float* __restrict__ att_dst1,
                                                 const float* __restrict__ att_src2,
                                                 const float* __restrict__ att_dst2,
                                                 unsigned short* __restrict__ W1T,
                                                 unsigned short* __restrict__ W2TE) {
    const int b = blockIdx.x;
    const int t = threadIdx.x;
    if (b < 128) {
        W1T[(size_t)t * 128 + b] = f2b(W1[(size_t)b * 256 + t]);
    } else if (b < 176) {
        int n = b - 128;                        // W2TE row, k = t
        float v;
        if (n < 32) {
            v = W2[(size_t)t * 32 + n];
        } else if (n == 32) {
            v = 0.f;
#pragma unroll 8
            for (int c = 0; c < 32; c++) v += W2[(size_t)t * 32 + c] * att_src2[c];
        } else if (n == 33) {
            v = 0.f;
#pragma unroll 8
            for (int c = 0; c < 32; c++) v += W2[(size_t)t * 32 + c] * att_dst2[c];
        } else {
            v = 0.f;
        }
        W2TE[(size_t)n * 256 + t] = f2b(v);
    } else {
        int idx = (b - 176) * 256 + t;          // 0..2047
        int col = idx >> 7;                     // 0..15
        int k = idx & 127;
        int h = col & 7;
        const float* att = (col < 8) ? att_src1 : att_dst1;
        float acc = 0.f;
#pragma unroll 8
        for (int j = 0; j < 32; j++) acc += W1[(size_t)k * 256 + h * 32 + j] * att[h * 32 + j];
        W1T[(size_t)(256 + col) * 128 + k] = f2b(acc);
    }
}

// ---------------- layer 1 GEMM via MFMA bf16: h1 = x0 @ W1 (+ fused logits) ----------------
__global__ __launch_bounds__(256) void gemm1_kernel(const float* __restrict__ x0,
                                                    const unsigned short* __restrict__ W1T,
                                                    unsigned short* __restrict__ h1,
                                                    float* __restrict__ a_src,
                                                    float* __restrict__ a_dst) {
    const int wv = threadIdx.x >> 6;
    const int lane = threadIdx.x & 63;
    const int quad = lane >> 4, c = lane & 15;
    const int base_m = blockIdx.x * 128 + wv * 32;
    bf16x8 af[2][4];
#pragma unroll
    for (int mt = 0; mt < 2; mt++) {
        int row = base_m + mt * 16 + c;
        int rowc = row < N ? row : N - 1;
        const float* ap = x0 + (size_t)rowc * 128 + quad * 8;
#pragma unroll
        for (int ks = 0; ks < 4; ks++) {
            float4 lo = *(const float4*)(ap + ks * 32);
            float4 hi = *(const float4*)(ap + ks * 32 + 4);
            bf16x8 f;
            f[0] = (short)f2b(lo.x); f[1] = (short)f2b(lo.y);
            f[2] = (short)f2b(lo.z); f[3] = (short)f2b(lo.w);
            f[4] = (short)f2b(hi.x); f[5] = (short)f2b(hi.y);
            f[6] = (short)f2b(hi.z); f[7] = (short)f2b(hi.w);
            af[mt][ks] = f;
        }
    }
    for (int nt = 0; nt < 17; nt++) {
        f32x4 acc0 = {0.f, 0.f, 0.f, 0.f};
        f32x4 acc1 = {0.f, 0.f, 0.f, 0.f};
#pragma unroll
        for (int ks = 0; ks < 4; ks++) {
            bf16x8 bf = *(const bf16x8*)(W1T + (size_t)(nt * 16 + c) * 128 + ks * 32 + quad * 8);
            acc0 = __builtin_amdgcn_mfma_f32_16x16x32_bf16(af[0][ks], bf, acc0, 0, 0, 0);
            acc1 = __builtin_amdgcn_mfma_f32_16x16x32_bf16(af[1][ks], bf, acc1, 0, 0, 0);
        }
        if (nt < 16) {
            const int col = nt * 16 + c;
#pragma unroll
            for (int r = 0; r < 4; r++) {
                int row0 = base_m + quad * 4 + r;
                if (row0 < N) h1[(size_t)row0 * 256 + col] = f2b(acc0[r]);
                int row1 = base_m + 16 + quad * 4 + r;
                if (row1 < N) h1[(size_t)row1 * 256 + col] = f2b(acc1[r]);
            }
        } else {
            float* dst = (c < 8) ? a_src : a_dst;
            int hh = c & 7;
#pragma unroll
            for (int r = 0; r < 4; r++) {
                int row0 = base_m + quad * 4 + r;
                if (row0 < N) dst[(size_t)row0 * 8 + hh] = acc0[r];
                int row1 = base_m + 16 + quad * 4 + r;
                if (row1 < N) dst[(size_t)row1 * 8 + hh] = acc1[r];
            }
        }
    }
}

// ---------------- layer 1 aggregate (wave/node, masked 4-chain) + fused layer-2 GEMM ----------------
__global__ __launch_bounds__(256) void seg1_kernel(const int* __restrict__ esrc,
                                                   const int* __restrict__ rofs,
                                                   const float* __restrict__ a_src,
                                                   const float* __restrict__ a_dst,
                                                   const unsigned short* __restrict__ h1,
                                                   const float* __restrict__ b1,
                                                   const unsigned short* __restrict__ W2TE,
                                                   unsigned short* __restrict__ h2,
                                                   float* __restrict__ a_src2,
                                                   float* __restrict__ a_dst2) {
    __shared__ unsigned short xls[4][256];   // 2 KB: this block's 4 x2 rows (bf16)
    const int wv = threadIdx.x >> 6;
    const int lane = threadIdx.x & 63;
    const int h = lane >> 3;
    const int n = blockIdx.x * 4 + wv;       // N % 4 == 0 -> always valid
    const int rs = rofs[n], re = rofs[n + 1];
    const float ad = a_dst[(size_t)n * 8 + h];
    float d0 = 0.f, d1 = 0.f, d2 = 0.f, d3 = 0.f;
    float4 A0 = {0, 0, 0, 0}, A1 = {0, 0, 0, 0}, A2 = {0, 0, 0, 0}, A3 = {0, 0, 0, 0};
    for (int j0 = rs; j0 < re; j0 += 4) {
        int cl = re - 1;
        int s0 = esrc[j0];
        int s1 = esrc[j0 + 1 < re ? j0 + 1 : cl];
        int s2 = esrc[j0 + 2 < re ? j0 + 2 : cl];
        int s3 = esrc[j0 + 3 < re ? j0 + 3 : cl];
        float as0 = a_src[(size_t)s0 * 8 + h];
        float as1 = a_src[(size_t)s1 * 8 + h];
        float as2 = a_src[(size_t)s2 * 8 + h];
        float as3 = a_src[(size_t)s3 * 8 + h];
        ushort4 hb0 = ((const ushort4*)(h1 + (size_t)s0 * 256))[lane];
        ushort4 hb1 = ((const ushort4*)(h1 + (size_t)s1 * 256))[lane];
        ushort4 hb2 = ((const ushort4*)(h1 + (size_t)s2 * 256))[lane];
        ushort4 hb3 = ((const ushort4*)(h1 + (size_t)s3 * 256))[lane];
        float w0 = __expf(lrelu(as0 + ad));
        float w1 = (j0 + 1 < re) ? __expf(lrelu(as1 + ad)) : 0.f;
        float w2 = (j0 + 2 < re) ? __expf(lrelu(as2 + ad)) : 0.f;
        float w3 = (j0 + 3 < re) ? __expf(lrelu(as3 + ad)) : 0.f;
        d0 += w0; d1 += w1; d2 += w2; d3 += w3;
        A0.x += w0 * b2f(hb0.x); A0.y += w0 * b2f(hb0.y); A0.z += w0 * b2f(hb0.z); A0.w += w0 * b2f(hb0.w);
        A1.x += w1 * b2f(hb1.x); A1.y += w1 * b2f(hb1.y); A1.z += w1 * b2f(hb1.z); A1.w += w1 * b2f(hb1.w);
        A2.x += w2 * b2f(hb2.x); A2.y += w2 * b2f(hb2.y); A2.z += w2 * b2f(hb2.z); A2.w += w2 * b2f(hb2.w);
        A3.x += w3 * b2f(hb3.x); A3.y += w3 * b2f(hb3.y); A3.z += w3 * b2f(hb3.z); A3.w += w3 * b2f(hb3.w);
    }
    float den = (d0 + d1) + (d2 + d3);
    float4 acc;
    acc.x = (A0.x + A1.x) + (A2.x + A3.x);
    acc.y = (A0.y + A1.y) + (A2.y + A3.y);
    acc.z = (A0.z + A1.z) + (A2.z + A3.z);
    acc.w = (A0.w + A1.w) + (A2.w + A3.w);
    const float inv = 1.0f / den;
    float4 bb = ((const float4*)b1)[lane];
    float vx = acc.x * inv + bb.x, vy = acc.y * inv + bb.y;
    float vz = acc.z * inv + bb.z, vw = acc.w * inv + bb.w;
    vx = vx > 0.f ? vx : 0.f; vy = vy > 0.f ? vy : 0.f;
    vz = vz > 0.f ? vz : 0.f; vw = vw > 0.f ? vw : 0.f;
    ushort4 o = {f2b(vx), f2b(vy), f2b(vz), f2b(vw)};
    ((ushort4*)(xls[wv]))[lane] = o;
    __syncthreads();
    // ---- fused layer-2 GEMM: [4 rows of x2] @ W2TE^T -> h2 + logits (wave 0 only) ----
    if (wv == 0) {
        const int quad = lane >> 4, c = lane & 15;
        f32x4 g0 = {0, 0, 0, 0}, g1 = {0, 0, 0, 0}, g2 = {0, 0, 0, 0};
        const bf16x8 za = {0, 0, 0, 0, 0, 0, 0, 0};
#pragma unroll
        for (int ks = 0; ks < 8; ks++) {
            bf16x8 a = (c < 4) ? *(const bf16x8*)(&xls[c][ks * 32 + quad * 8]) : za;
            bf16x8 bA = *(const bf16x8*)(W2TE + (size_t)c * 256 + ks * 32 + quad * 8);
            bf16x8 bB = *(const bf16x8*)(W2TE + (size_t)(16 + c) * 256 + ks * 32 + quad * 8);
            bf16x8 bC = *(const bf16x8*)(W2TE + (size_t)(32 + c) * 256 + ks * 32 + quad * 8);
            g0 = __builtin_amdgcn_mfma_f32_16x16x32_bf16(a, bA, g0, 0, 0, 0);
            g1 = __builtin_amdgcn_mfma_f32_16x16x32_bf16(a, bB, g1, 0, 0, 0);
            g2 = __builtin_amdgcn_mfma_f32_16x16x32_bf16(a, bC, g2, 0, 0, 0);
        }
        // D: col=c, row=quad*4+r; valid rows (nodes) 0..3 live in quad 0
        if (quad == 0) {
#pragma unroll
            for (int r = 0; r < 4; r++) {
                int node = blockIdx.x * 4 + r;
                h2[(size_t)node * 32 + c] = f2b(g0[r]);
                h2[(size_t)node * 32 + 16 + c] = f2b(g1[r]);
                if (c == 0) a_src2[node] = g2[r];
                if (c == 1) a_dst2[node] = g2[r];
            }
        }
    }
}

// ---------------- layer 2 aggregate + final linear fused: half-wave/node, 8 chains ----------------
__global__ __launch_bounds__(256) void seg2_kernel(const int* __restrict__ esrc,
                                                   const int* __restrict__ rofs,
                                                   const float* __restrict__ a_src2,
                                                   const float* __restrict__ a_dst2,
                                                   const unsigned short* __restrict__ h2,
                                                   const float* __restrict__ b2,
                                                   const float* __restrict__ linW,
                                                   const float* __restrict__ linb,
                                                   float* __restrict__ out) {
    __shared__ float lws[32 * 40];
    __shared__ float vbuf[8][32];
    const int t = threadIdx.x;
    for (int i = t; i < 1280; i += 256) lws[i] = linW[i];
    const int n8 = t >> 5;
    const int c = t & 31;
    const int n = blockIdx.x * 8 + n8;      // N % 8 == 0 -> always valid
    const int rs = rofs[n], re = rofs[n + 1];
    const float ad = a_dst2[n];
    float d[8] = {0, 0, 0, 0, 0, 0, 0, 0};
    float A[8] = {0, 0, 0, 0, 0, 0, 0, 0};
    for (int j0 = rs; j0 < re; j0 += 8) {
        int sidx[8];
#pragma unroll
        for (int k = 0; k < 8; k++) {
            int j = j0 + k;
            sidx[k] = esrc[j < re ? j : re - 1];
        }
        unsigned short hb[8];
        float as[8];
#pragma unroll
        for (int k = 0; k < 8; k++) {
            hb[k] = h2[(size_t)sidx[k] * 32 + c];
            as[k] = a_src2[sidx[k]];
        }
#pragma unroll
        for (int k = 0; k < 8; k++) {
            float w = (j0 + k < re) ? __expf(lrelu(as[k] + ad)) : 0.f;
            d[k] += w;
            A[k] += w * b2f(hb[k]);
        }
    }
    float den = ((d[0] + d[1]) + (d[2] + d[3])) + ((d[4] + d[5]) + (d[6] + d[7]));
    float acc = ((A[0] + A[1]) + (A[2] + A[3])) + ((A[4] + A[5]) + (A[6] + A[7]));
    vbuf[n8][c] = acc / den + b2[c];
    __syncthreads();
    for (int idx = t; idx < 320; idx += 256) {
        int nn = idx / 40, o = idx - nn * 40;
        float s = linb[o];
#pragma unroll
        for (int ci = 0; ci < 32; ci++) s += vbuf[nn][ci] * lws[ci * 40 + o];
        out[(size_t)blockIdx.x * 320 + idx] = s;
    }
}

extern "C" void kernel_launch(void* const* d_in, const int* in_sizes, int n_in,
                              void* d_out, int out_size, void* d_ws, size_t ws_size,
                              hipStream_t stream) {
    const float* x0       = (const float*)d_in[0];
    const float* W1       = (const float*)d_in[1];
    const float* att_src1 = (const float*)d_in[2];
    const float* att_dst1 = (const float*)d_in[3];
    const float* b1       = (const float*)d_in[4];
    const float* W2       = (const float*)d_in[5];
    const float* att_src2 = (const float*)d_in[6];
    const float* att_dst2 = (const float*)d_in[7];
    const float* b2       = (const float*)d_in[8];
    const float* linW     = (const float*)d_in[9];
    const float* linb     = (const float*)d_in[10];
    const int*   ei       = (const int*)d_in[11];
    float* out = (float*)d_out;
    float* ws  = (float*)d_ws;

    unsigned short* h1   = (unsigned short*)ws;                  // 25.6M bf16 = 12.8M floats
    float* a_src1        = ws + 12800000;                        // 0.8M
    float* a_dst1        = ws + 13600000;                        // 0.8M
    unsigned short* h2   = (unsigned short*)(ws + 14400000);     // 3.2M bf16
    float* a_src2        = ws + 16000000;                        // 0.1M
    float* a_dst2        = ws + 16100000;                        // 0.1M
    unsigned short* W1T  = (unsigned short*)(ws + 16200000);     // 272*128 bf16
    unsigned short* W2TE = (unsigned short*)(ws + 16220000);     // 48*256 bf16
    int*   hist          = (int*)(ws + 16230000);                // 0.1M
    int*   rofs          = (int*)(ws + 16330000);                // N+1
    int*   cursor        = (int*)(ws + 16440000);                // 0.1M
    int*   bsum          = (int*)(ws + 16540000);                // 512
    int*   esrc          = (int*)(ws + 16541000);                // 1.1M

    hipMemsetAsync(hist, 0, (size_t)N * 4, stream);

    hist_kernel<<<(ETOT + 255) / 256, 256, 0, stream>>>(ei, hist);
    scan1_kernel<<<NB1, 256, 0, stream>>>(hist, rofs, bsum);
    scan2_kernel<<<1, 512, 0, stream>>>(bsum);
    scan3_kernel<<<NB1, 256, 0, stream>>>(rofs, bsum, cursor);
    scatter_kernel<<<(ETOT + 255) / 256, 256, 0, stream>>>(ei, cursor, esrc);

    wt_kernel<<<184, 256, 0, stream>>>(W1, W2, att_src1, att_dst1, att_src2, att_dst2, W1T, W2TE);
    gemm1_kernel<<<(N + 127) / 128, 256, 0, stream>>>(x0, W1T, h1, a_src1, a_dst1);
    seg1_kernel<<<N / 4, 256, 0, stream>>>(esrc, rofs, a_src1, a_dst1, h1, b1, W2TE, h2, a_src2, a_dst2);
    seg2_kernel<<<N / 8, 256, 0, stream>>>(esrc, rofs, a_src2, a_dst2, h2, b2, linW, linb, out);
}

// Round 9
// 437.379 us; speedup vs baseline: 1.0989x; 1.0989x over previous
//
#include <hip/hip_runtime.h>

#define N 100000
#define E 1000000
#define ETOT 1100000   // E + N self-loops
#define NB1 391        // ceil(N/256)
#define NBE 4297       // ceil(ETOT/256)

typedef __attribute__((ext_vector_type(8))) short bf16x8;
typedef __attribute__((ext_vector_type(4))) float f32x4;

__device__ __forceinline__ float lrelu(float x) { return x > 0.f ? x : 0.2f * x; }
// f32 -> bf16 bits, round-to-nearest-even
__device__ __forceinline__ unsigned short f2b(float x) {
    unsigned u = __float_as_uint(x);
    return (unsigned short)((u + 0x7FFFu + ((u >> 16) & 1u)) >> 16);
}
__device__ __forceinline__ float b2f(unsigned short v) {
    return __uint_as_float(((unsigned)v) << 16);
}

// ---------------- CSR histogram + weight prep (independent work, one dispatch) ----------------
// blocks 0..NBE-1: edge histogram
// blocks NBE..NBE+127: W1T transpose row; NBE+128..NBE+159: W2T; NBE+160..NBE+167: W1 logit fold
__global__ __launch_bounds__(256) void prep_kernel(const int* __restrict__ ei,
                                                   int* __restrict__ hist,
                                                   const float* __restrict__ W1,
                                                   const float* __restrict__ W2,
                                                   const float* __restrict__ att_src1,
                                                   const float* __restrict__ att_dst1,
                                                   unsigned short* __restrict__ W1T,
                                                   unsigned short* __restrict__ W2T) {
    const int b = blockIdx.x;
    const int t = threadIdx.x;
    if (b < NBE) {
        const int e = b * 256 + t;
        if (e < ETOT) {
            int d = (e < E) ? ei[E + e] : (e - E);
            atomicAdd(&hist[d], 1);
        }
        return;
    }
    const int bb = b - NBE;
    if (bb < 128) {
        W1T[(size_t)t * 128 + bb] = f2b(W1[(size_t)bb * 256 + t]);
    } else if (bb < 160) {
        int n = bb - 128;
        W2T[(size_t)n * 256 + t] = f2b(W2[(size_t)t * 32 + n]);
    } else {
        int idx = (bb - 160) * 256 + t;         // 0..2047
        int col = idx >> 7;                     // 0..15
        int k = idx & 127;
        int h = col & 7;
        const float* att = (col < 8) ? att_src1 : att_dst1;
        float acc = 0.f;
#pragma unroll 8
        for (int j = 0; j < 32; j++) acc += W1[(size_t)k * 256 + h * 32 + j] * att[h * 32 + j];
        W1T[(size_t)(256 + col) * 128 + k] = f2b(acc);
    }
}

__global__ __launch_bounds__(256) void scan1_kernel(const int* __restrict__ hist,
                                                    int* __restrict__ rofs,
                                                    int* __restrict__ bsum) {
    __shared__ int sm[256];
    const int t = threadIdx.x;
    const int i = blockIdx.x * 256 + t;
    int v = (i < N) ? hist[i] : 0;
    sm[t] = v;
    __syncthreads();
#pragma unroll
    for (int off = 1; off < 256; off <<= 1) {
        int x = (t >= off) ? sm[t - off] : 0;
        __syncthreads();
        sm[t] += x;
        __syncthreads();
    }
    if (i < N) rofs[i] = sm[t] - v;
    if (t == 255) bsum[blockIdx.x] = sm[255];
}

__global__ __launch_bounds__(512) void scan2_kernel(int* __restrict__ bsum) {
    __shared__ int sm[512];
    const int t = threadIdx.x;
    int v = (t < NB1) ? bsum[t] : 0;
    sm[t] = v;
    __syncthreads();
#pragma unroll
    for (int off = 1; off < 512; off <<= 1) {
        int x = (t >= off) ? sm[t - off] : 0;
        __syncthreads();
        sm[t] += x;
        __syncthreads();
    }
    if (t < NB1) bsum[t] = sm[t] - v;
}

__global__ __launch_bounds__(256) void scan3_kernel(int* __restrict__ rofs,
                                                    const int* __restrict__ bsum,
                                                    int* __restrict__ cursor) {
    const int i = blockIdx.x * 256 + threadIdx.x;
    if (i < N) {
        int r = rofs[i] + bsum[blockIdx.x];
        rofs[i] = r;
        cursor[i] = r;
    }
    if (i == 0) rofs[N] = ETOT;
}

__global__ __launch_bounds__(256) void scatter_kernel(const int* __restrict__ ei,
                                                      int* __restrict__ cursor,
                                                      int* __restrict__ esrc) {
    const int e = blockIdx.x * 256 + threadIdx.x;
    if (e >= ETOT) return;
    int s, d;
    if (e < E) { s = ei[e]; d = ei[E + e]; } else { s = d = e - E; }
    int pos = atomicAdd(&cursor[d], 1);
    esrc[pos] = s;
}

// ---------------- layer 1 GEMM via MFMA bf16: h1 = x0 @ W1 (+ fused logits) ----------------
__global__ __launch_bounds__(256) void gemm1_kernel(const float* __restrict__ x0,
                                                    const unsigned short* __restrict__ W1T,
                                                    unsigned short* __restrict__ h1,
                                                    float* __restrict__ a_src,
                                                    float* __restrict__ a_dst) {
    const int wv = threadIdx.x >> 6;
    const int lane = threadIdx.x & 63;
    const int quad = lane >> 4, c = lane & 15;
    const int base_m = blockIdx.x * 128 + wv * 32;
    bf16x8 af[2][4];
#pragma unroll
    for (int mt = 0; mt < 2; mt++) {
        int row = base_m + mt * 16 + c;
        int rowc = row < N ? row : N - 1;
        const float* ap = x0 + (size_t)rowc * 128 + quad * 8;
#pragma unroll
        for (int ks = 0; ks < 4; ks++) {
            float4 lo = *(const float4*)(ap + ks * 32);
            float4 hi = *(const float4*)(ap + ks * 32 + 4);
            bf16x8 f;
            f[0] = (short)f2b(lo.x); f[1] = (short)f2b(lo.y);
            f[2] = (short)f2b(lo.z); f[3] = (short)f2b(lo.w);
            f[4] = (short)f2b(hi.x); f[5] = (short)f2b(hi.y);
            f[6] = (short)f2b(hi.z); f[7] = (short)f2b(hi.w);
            af[mt][ks] = f;
        }
    }
    for (int nt = 0; nt < 17; nt++) {
        f32x4 acc0 = {0.f, 0.f, 0.f, 0.f};
        f32x4 acc1 = {0.f, 0.f, 0.f, 0.f};
#pragma unroll
        for (int ks = 0; ks < 4; ks++) {
            bf16x8 bf = *(const bf16x8*)(W1T + (size_t)(nt * 16 + c) * 128 + ks * 32 + quad * 8);
            acc0 = __builtin_amdgcn_mfma_f32_16x16x32_bf16(af[0][ks], bf, acc0, 0, 0, 0);
            acc1 = __builtin_amdgcn_mfma_f32_16x16x32_bf16(af[1][ks], bf, acc1, 0, 0, 0);
        }
        if (nt < 16) {
            const int col = nt * 16 + c;
#pragma unroll
            for (int r = 0; r < 4; r++) {
                int row0 = base_m + quad * 4 + r;
                if (row0 < N) h1[(size_t)row0 * 256 + col] = f2b(acc0[r]);
                int row1 = base_m + 16 + quad * 4 + r;
                if (row1 < N) h1[(size_t)row1 * 256 + col] = f2b(acc1[r]);
            }
        } else {
            float* dst = (c < 8) ? a_src : a_dst;
            int hh = c & 7;
#pragma unroll
            for (int r = 0; r < 4; r++) {
                int row0 = base_m + quad * 4 + r;
                if (row0 < N) dst[(size_t)row0 * 8 + hh] = acc0[r];
                int row1 = base_m + 16 + quad * 4 + r;
                if (row1 < N) dst[(size_t)row1 * 8 + hh] = acc1[r];
            }
        }
    }
}

// ---------------- layer 1 aggregate: wave/node, masked 4-chain (no serial tail, no epilogue) ----------------
__global__ __launch_bounds__(256) void seg1_kernel(const int* __restrict__ esrc,
                                                   const int* __restrict__ rofs,
                                                   const float* __restrict__ a_src,
                                                   const float* __restrict__ a_dst,
                                                   const unsigned short* __restrict__ h1,
                                                   const float* __restrict__ b1,
                                                   unsigned short* __restrict__ x2) {
    const int n = (blockIdx.x * 256 + threadIdx.x) >> 6;   // N % 4 == 0 -> always valid
    const int lane = threadIdx.x & 63;
    const int h = lane >> 3;
    const int rs = rofs[n], re = rofs[n + 1];
    const float ad = a_dst[(size_t)n * 8 + h];
    float d0 = 0.f, d1 = 0.f, d2 = 0.f, d3 = 0.f;
    float4 A0 = {0, 0, 0, 0}, A1 = {0, 0, 0, 0}, A2 = {0, 0, 0, 0}, A3 = {0, 0, 0, 0};
    for (int j0 = rs; j0 < re; j0 += 4) {
        const int cl = re - 1;
        int s0 = esrc[j0];
        int s1 = esrc[j0 + 1 < re ? j0 + 1 : cl];
        int s2 = esrc[j0 + 2 < re ? j0 + 2 : cl];
        int s3 = esrc[j0 + 3 < re ? j0 + 3 : cl];
        float as0 = a_src[(size_t)s0 * 8 + h];
        float as1 = a_src[(size_t)s1 * 8 + h];
        float as2 = a_src[(size_t)s2 * 8 + h];
        float as3 = a_src[(size_t)s3 * 8 + h];
        ushort4 hb0 = ((const ushort4*)(h1 + (size_t)s0 * 256))[lane];
        ushort4 hb1 = ((const ushort4*)(h1 + (size_t)s1 * 256))[lane];
        ushort4 hb2 = ((const ushort4*)(h1 + (size_t)s2 * 256))[lane];
        ushort4 hb3 = ((const ushort4*)(h1 + (size_t)s3 * 256))[lane];
        float w0 = __expf(lrelu(as0 + ad));
        float w1 = (j0 + 1 < re) ? __expf(lrelu(as1 + ad)) : 0.f;
        float w2 = (j0 + 2 < re) ? __expf(lrelu(as2 + ad)) : 0.f;
        float w3 = (j0 + 3 < re) ? __expf(lrelu(as3 + ad)) : 0.f;
        d0 += w0; d1 += w1; d2 += w2; d3 += w3;
        A0.x += w0 * b2f(hb0.x); A0.y += w0 * b2f(hb0.y); A0.z += w0 * b2f(hb0.z); A0.w += w0 * b2f(hb0.w);
        A1.x += w1 * b2f(hb1.x); A1.y += w1 * b2f(hb1.y); A1.z += w1 * b2f(hb1.z); A1.w += w1 * b2f(hb1.w);
        A2.x += w2 * b2f(hb2.x); A2.y += w2 * b2f(hb2.y); A2.z += w2 * b2f(hb2.z); A2.w += w2 * b2f(hb2.w);
        A3.x += w3 * b2f(hb3.x); A3.y += w3 * b2f(hb3.y); A3.z += w3 * b2f(hb3.z); A3.w += w3 * b2f(hb3.w);
    }
    float den = (d0 + d1) + (d2 + d3);
    float4 acc;
    acc.x = (A0.x + A1.x) + (A2.x + A3.x);
    acc.y = (A0.y + A1.y) + (A2.y + A3.y);
    acc.z = (A0.z + A1.z) + (A2.z + A3.z);
    acc.w = (A0.w + A1.w) + (A2.w + A3.w);
    const float inv = 1.0f / den;
    float4 bb = ((const float4*)b1)[lane];
    float vx = acc.x * inv + bb.x, vy = acc.y * inv + bb.y;
    float vz = acc.z * inv + bb.z, vw = acc.w * inv + bb.w;
    vx = vx > 0.f ? vx : 0.f; vy = vy > 0.f ? vy : 0.f;
    vz = vz > 0.f ? vz : 0.f; vw = vw > 0.f ? vw : 0.f;
    ushort4 o = {f2b(vx), f2b(vy), f2b(vz), f2b(vw)};
    ((ushort4*)(x2 + (size_t)n * 256))[lane] = o;
}

// ---------------- layer 2 GEMM via MFMA: h2 = x2 @ W2 (256->32), fused logits ----------------
__global__ __launch_bounds__(256) void gemm2_kernel(const unsigned short* __restrict__ x2,
                                                    const unsigned short* __restrict__ W2T,
                                                    const float* __restrict__ att_src2,
                                                    const float* __restrict__ att_dst2,
                                                    unsigned short* __restrict__ h2,
                                                    float* __restrict__ a_src2,
                                                    float* __restrict__ a_dst2) {
    const int wv = threadIdx.x >> 6;
    const int lane = threadIdx.x & 63;
    const int quad = lane >> 4, c = lane & 15;
    const int base_m = blockIdx.x * 128 + wv * 32;
    f32x4 acc[2][2] = {{{0, 0, 0, 0}, {0, 0, 0, 0}}, {{0, 0, 0, 0}, {0, 0, 0, 0}}};
#pragma unroll
    for (int ks = 0; ks < 8; ks++) {
        bf16x8 b0 = *(const bf16x8*)(W2T + (size_t)c * 256 + ks * 32 + quad * 8);
        bf16x8 b1 = *(const bf16x8*)(W2T + (size_t)(16 + c) * 256 + ks * 32 + quad * 8);
#pragma unroll
        for (int mt = 0; mt < 2; mt++) {
            int row = base_m + mt * 16 + c;
            int rowc = row < N ? row : N - 1;
            bf16x8 a = *(const bf16x8*)(x2 + (size_t)rowc * 256 + ks * 32 + quad * 8);
            acc[mt][0] = __builtin_amdgcn_mfma_f32_16x16x32_bf16(a, b0, acc[mt][0], 0, 0, 0);
            acc[mt][1] = __builtin_amdgcn_mfma_f32_16x16x32_bf16(a, b1, acc[mt][1], 0, 0, 0);
        }
    }
    float as0 = att_src2[c], as1 = att_src2[16 + c];
    float ad0 = att_dst2[c], ad1 = att_dst2[16 + c];
#pragma unroll
    for (int mt = 0; mt < 2; mt++) {
#pragma unroll
        for (int r = 0; r < 4; r++) {
            int row = base_m + mt * 16 + quad * 4 + r;
            float v0 = acc[mt][0][r], v1 = acc[mt][1][r];
            float ps = v0 * as0 + v1 * as1;
            float pd = v0 * ad0 + v1 * ad1;
#pragma unroll
            for (int off = 1; off < 16; off <<= 1) {
                ps += __shfl_xor(ps, off, 64);
                pd += __shfl_xor(pd, off, 64);
            }
            if (row < N) {
                h2[(size_t)row * 32 + c] = f2b(v0);
                h2[(size_t)row * 32 + 16 + c] = f2b(v1);
                if (c == 0) { a_src2[row] = ps; a_dst2[row] = pd; }
            }
        }
    }
}

// ---------------- layer 2 aggregate + final linear fused: half-wave/node, masked 8 chains ----------------
__global__ __launch_bounds__(256) void seg2_kernel(const int* __restrict__ esrc,
                                                   const int* __restrict__ rofs,
                                                   const float* __restrict__ a_src2,
                                                   const float* __restrict__ a_dst2,
                                                   const unsigned short* __restrict__ h2,
                                                   const float* __restrict__ b2,
                                                   const float* __restrict__ linW,
                                                   const float* __restrict__ linb,
                                                   float* __restrict__ out) {
    __shared__ float lws[32 * 40];
    __shared__ float vbuf[8][32];
    const int t = threadIdx.x;
    for (int i = t; i < 1280; i += 256) lws[i] = linW[i];
    const int n8 = t >> 5;
    const int c = t & 31;
    const int n = blockIdx.x * 8 + n8;      // N % 8 == 0 -> always valid
    const int rs = rofs[n], re = rofs[n + 1];
    const float ad = a_dst2[n];
    float d[8] = {0, 0, 0, 0, 0, 0, 0, 0};
    float A[8] = {0, 0, 0, 0, 0, 0, 0, 0};
    for (int j0 = rs; j0 < re; j0 += 8) {
        int sidx[8];
#pragma unroll
        for (int k = 0; k < 8; k++) {
            int j = j0 + k;
            sidx[k] = esrc[j < re ? j : re - 1];
        }
        unsigned short hb[8];
        float as[8];
#pragma unroll
        for (int k = 0; k < 8; k++) {
            hb[k] = h2[(size_t)sidx[k] * 32 + c];
            as[k] = a_src2[sidx[k]];
        }
#pragma unroll
        for (int k = 0; k < 8; k++) {
            float w = (j0 + k < re) ? __expf(lrelu(as[k] + ad)) : 0.f;
            d[k] += w;
            A[k] += w * b2f(hb[k]);
        }
    }
    float den = ((d[0] + d[1]) + (d[2] + d[3])) + ((d[4] + d[5]) + (d[6] + d[7]));
    float acc = ((A[0] + A[1]) + (A[2] + A[3])) + ((A[4] + A[5]) + (A[6] + A[7]));
    vbuf[n8][c] = acc / den + b2[c];
    __syncthreads();
    for (int idx = t; idx < 320; idx += 256) {
        int nn = idx / 40, o = idx - nn * 40;
        float s = linb[o];
#pragma unroll
        for (int ci = 0; ci < 32; ci++) s += vbuf[nn][ci] * lws[ci * 40 + o];
        out[(size_t)blockIdx.x * 320 + idx] = s;
    }
}

extern "C" void kernel_launch(void* const* d_in, const int* in_sizes, int n_in,
                              void* d_out, int out_size, void* d_ws, size_t ws_size,
                              hipStream_t stream) {
    const float* x0       = (const float*)d_in[0];
    const float* W1       = (const float*)d_in[1];
    const float* att_src1 = (const float*)d_in[2];
    const float* att_dst1 = (const float*)d_in[3];
    const float* b1       = (const float*)d_in[4];
    const float* W2       = (const float*)d_in[5];
    const float* att_src2 = (const float*)d_in[6];
    const float* att_dst2 = (const float*)d_in[7];
    const float* b2       = (const float*)d_in[8];
    const float* linW     = (const float*)d_in[9];
    const float* linb     = (const float*)d_in[10];
    const int*   ei       = (const int*)d_in[11];
    float* out = (float*)d_out;
    float* ws  = (float*)d_ws;

    unsigned short* h1   = (unsigned short*)ws;                  // 25.6M bf16 = 12.8M floats
    unsigned short* x2   = (unsigned short*)(ws + 12800000);     // 25.6M bf16
    float* a_src1        = ws + 25600000;                        // 0.8M
    float* a_dst1        = ws + 26400000;                        // 0.8M
    unsigned short* h2   = (unsigned short*)(ws + 27200000);     // 3.2M bf16
    float* a_src2        = ws + 28800000;                        // 0.1M
    float* a_dst2        = ws + 28900000;                        // 0.1M
    unsigned short* W1T  = (unsigned short*)(ws + 29000000);     // 272*128 bf16
    unsigned short* W2T  = (unsigned short*)(ws + 29020000);     // 32*256 bf16
    int*   hist          = (int*)(ws + 29030000);                // 0.1M
    int*   rofs          = (int*)(ws + 29130000);                // N+1
    int*   cursor        = (int*)(ws + 29240000);                // 0.1M
    int*   bsum          = (int*)(ws + 29340000);                // 512
    int*   esrc          = (int*)(ws + 29341000);                // 1.1M

    hipMemsetAsync(hist, 0, (size_t)N * 4, stream);

    prep_kernel<<<NBE + 168, 256, 0, stream>>>(ei, hist, W1, W2, att_src1, att_dst1, W1T, W2T);
    scan1_kernel<<<NB1, 256, 0, stream>>>(hist, rofs, bsum);
    scan2_kernel<<<1, 512, 0, stream>>>(bsum);
    scan3_kernel<<<NB1, 256, 0, stream>>>(rofs, bsum, cursor);
    scatter_kernel<<<(ETOT + 255) / 256, 256, 0, stream>>>(ei, cursor, esrc);

    gemm1_kernel<<<(N + 127) / 128, 256, 0, stream>>>(x0, W1T, h1, a_src1, a_dst1);
    seg1_kernel<<<N / 4, 256, 0, stream>>>(esrc, rofs, a_src1, a_dst1, h1, b1, x2);
    gemm2_kernel<<<(N + 127) / 128, 256, 0, stream>>>(x2, W2T, att_src2, att_dst2, h2, a_src2, a_dst2);
    seg2_kernel<<<N / 8, 256, 0, stream>>>(esrc, rofs, a_src2, a_dst2, h2, b2, linW, linb, out);
}